// Round 1
// baseline (1807.725 us; speedup 1.0000x reference)
//
#include <hip/hip_runtime.h>
#include <hip/hip_bf16.h>
#include <math.h>

#define N_NODES 50000
#define N_EDGES 500000
#define DIM     128
#define NLAYER  4
#define NEFEAT  7

static constexpr float LN_EPS    = 1e-5f;
static constexpr float ATT_SCALE = 0.17677669529663687f;  // 1/sqrt(32)

static __device__ __forceinline__ float leaky(float x){ return x >= 0.f ? x : 0.01f*x; }

// ---------------- init h = node_table[0] broadcast ----------------
__global__ void init_h_kernel(const float* __restrict__ node_table, float* __restrict__ h){
    int i = blockIdx.x*blockDim.x + threadIdx.x;
    if (i < N_NODES*DIM) h[i] = node_table[i & (DIM-1)];
}

// ---------------- CSR build ----------------
__global__ void zero2_kernel(int* __restrict__ a, int* __restrict__ b){
    int i = blockIdx.x*blockDim.x + threadIdx.x;
    if (i < N_NODES){ a[i] = 0; b[i] = 0; }
}

__global__ void count_kernel(const int* __restrict__ dst, int* __restrict__ cnt){
    int e = blockIdx.x*blockDim.x + threadIdx.x;
    if (e < N_EDGES) atomicAdd(&cnt[dst[e]], 1);
}

__global__ void scan_kernel(const int* __restrict__ cnt, int* __restrict__ rowptr){
    __shared__ int sd[1024];
    __shared__ int running;
    if (threadIdx.x == 0) running = 0;
    __syncthreads();
    for (int base = 0; base < N_NODES; base += 1024){
        int i = base + (int)threadIdx.x;
        int v = (i < N_NODES) ? cnt[i] : 0;
        sd[threadIdx.x] = v;
        __syncthreads();
        for (int off = 1; off < 1024; off <<= 1){
            int t = (threadIdx.x >= (unsigned)off) ? sd[threadIdx.x - off] : 0;
            __syncthreads();
            sd[threadIdx.x] += t;
            __syncthreads();
        }
        if (i < N_NODES) rowptr[i] = running + sd[threadIdx.x] - v;  // exclusive
        int tot = sd[1023];
        __syncthreads();
        if (threadIdx.x == 0) running += tot;
        __syncthreads();
    }
    if (threadIdx.x == 0) rowptr[N_NODES] = running;
}

__global__ void scatter_kernel(const int* __restrict__ src, const int* __restrict__ dst,
                               const float* __restrict__ edge_attr,
                               const int* __restrict__ rowptr, int* __restrict__ fill,
                               int* __restrict__ srcs, float* __restrict__ eas){
    int e = blockIdx.x*blockDim.x + threadIdx.x;
    if (e >= N_EDGES) return;
    int d   = dst[e];
    int pos = rowptr[d] + atomicAdd(&fill[d], 1);
    srcs[pos] = src[e];
    float*       o = eas + (size_t)pos*8;
    const float* a = edge_attr + (size_t)e*NEFEAT;
    #pragma unroll
    for (int c = 0; c < NEFEAT; ++c) o[c] = a[c];
    o[7] = 1.0f;   // bias slot
}

// ---------------- Weff = [Wee@We_l ; bee@We_l + be_l]  (8 x 128) ----------------
__global__ void weff_kernel(const float* __restrict__ Wee, const float* __restrict__ bee,
                            const float* __restrict__ We_l, const float* __restrict__ be_l,
                            float* __restrict__ Weff){
    int d = threadIdx.x;  // 128 threads
    for (int c = 0; c < NEFEAT; ++c){
        float s = 0.f;
        for (int t = 0; t < DIM; ++t) s += Wee[c*DIM + t] * We_l[t*DIM + d];
        Weff[c*DIM + d] = s;
    }
    float s = 0.f;
    for (int t = 0; t < DIM; ++t) s += bee[t] * We_l[t*DIM + d];
    Weff[7*DIM + d] = s + be_l[d];
}

// ---------------- fused QKVS GEMM: [N,128] @ [128,128]x4 ----------------
__global__ __launch_bounds__(256) void gemm_qkvs_kernel(
    const float* __restrict__ h,
    const float* __restrict__ Wq, const float* __restrict__ bq,
    const float* __restrict__ Wk, const float* __restrict__ bk,
    const float* __restrict__ Wv, const float* __restrict__ bv,
    const float* __restrict__ Ws, const float* __restrict__ bs,
    float* __restrict__ q, float* __restrict__ k,
    float* __restrict__ v, float* __restrict__ s)
{
    __shared__ float hs[64][DIM+2];
    int row0 = blockIdx.x*64;
    for (int i = threadIdx.x; i < 64*32; i += 256){
        int r = i >> 5, c4 = (i & 31)*4;
        int row = row0 + r;
        float4 val = make_float4(0.f,0.f,0.f,0.f);
        if (row < N_NODES) val = *(const float4*)(h + (size_t)row*DIM + c4);
        hs[r][c4+0]=val.x; hs[r][c4+1]=val.y; hs[r][c4+2]=val.z; hs[r][c4+3]=val.w;
    }
    __syncthreads();
    int rowg = threadIdx.x >> 5;   // 8 groups x 8 rows
    int colg = threadIdx.x & 31;   // 32 groups x 4 cols
    int jj = colg*4;
    for (int ct = 0; ct < 4; ++ct){
        const float* W; const float* B; float* O;
        if      (ct==0){ W=Wq; B=bq; O=q; }
        else if (ct==1){ W=Wk; B=bk; O=k; }
        else if (ct==2){ W=Wv; B=bv; O=v; }
        else           { W=Ws; B=bs; O=s; }
        float acc[8][4];
        #pragma unroll
        for (int r=0;r<8;++r){ acc[r][0]=0.f; acc[r][1]=0.f; acc[r][2]=0.f; acc[r][3]=0.f; }
        for (int kk = 0; kk < DIM; kk += 2){
            float4 wA = *(const float4*)(W + (size_t)kk*DIM + jj);
            float4 wB = *(const float4*)(W + (size_t)(kk+1)*DIM + jj);
            #pragma unroll
            for (int r=0;r<8;++r){
                float2 hv = *(const float2*)&hs[rowg*8+r][kk];
                acc[r][0] += hv.x*wA.x + hv.y*wB.x;
                acc[r][1] += hv.x*wA.y + hv.y*wB.y;
                acc[r][2] += hv.x*wA.z + hv.y*wB.z;
                acc[r][3] += hv.x*wA.w + hv.y*wB.w;
            }
        }
        float4 bb = *(const float4*)(B + jj);
        #pragma unroll
        for (int r=0;r<8;++r){
            int row = row0 + rowg*8 + r;
            if (row < N_NODES){
                float4 o = make_float4(acc[r][0]+bb.x, acc[r][1]+bb.y, acc[r][2]+bb.z, acc[r][3]+bb.w);
                *(float4*)(O + (size_t)row*DIM + jj) = o;
            }
        }
    }
}

// ---------------- attention: one wave per destination node ----------------
__global__ __launch_bounds__(256) void attn_kernel(
    const float* __restrict__ q, const float* __restrict__ k, const float* __restrict__ v,
    const float* __restrict__ Weff, const int* __restrict__ rowptr,
    const int* __restrict__ srcs, const float* __restrict__ eas,
    float* __restrict__ satt)
{
    __shared__ float wf[8][DIM];
    for (int i = threadIdx.x; i < 8*DIM; i += 256) ((float*)wf)[i] = Weff[i];
    __syncthreads();
    int wv = threadIdx.x >> 6, lane = threadIdx.x & 63;
    int n = blockIdx.x*4 + wv;
    if (n >= N_NODES) return;
    int d0 = lane*2;
    const float2 qv = *(const float2*)(q + (size_t)n*DIM + d0);
    int beg = rowptr[n], end = rowptr[n+1];
    float m = -INFINITY, den = 0.f, a0 = 0.f, a1 = 0.f;
    for (int i = beg; i < end; ++i){
        int sv = srcs[i];
        float2 kv = *(const float2*)(k + (size_t)sv*DIM + d0);
        float2 vv = *(const float2*)(v + (size_t)sv*DIM + d0);
        const float* ea = eas + (size_t)i*8;
        float e0 = 0.f, e1 = 0.f;
        #pragma unroll
        for (int c = 0; c < 8; ++c){
            float ec = ea[c];
            float2 wc = *(const float2*)&wf[c][d0];
            e0 += ec*wc.x; e1 += ec*wc.y;
        }
        float part = qv.x*(kv.x+e0) + qv.y*(kv.y+e1);
        part += __shfl_xor(part, 1);
        part += __shfl_xor(part, 2);
        part += __shfl_xor(part, 4);
        part += __shfl_xor(part, 8);   // per-head (16-lane) dot
        float alpha = part * ATT_SCALE;
        float nm = fmaxf(m, alpha);
        float f  = __expf(m - nm);     // m=-inf on first edge -> 0
        float p  = __expf(alpha - nm);
        den = den*f + p;
        a0  = a0*f  + p*(vv.x+e0);
        a1  = a1*f  + p*(vv.y+e1);
        m = nm;
    }
    float inv = (den > 0.f) ? 1.f/den : 0.f;   // empty segment -> zeros
    float2 sv2 = *(const float2*)(satt + (size_t)n*DIM + d0);
    float2 o = make_float2(a0*inv + sv2.x, a1*inv + sv2.y);
    *(float2*)(satt + (size_t)n*DIM + d0) = o;
}

// ---------------- x1 = LN(h + att_out) ----------------
__global__ __launch_bounds__(256) void x1_kernel(
    const float* __restrict__ h, const float* __restrict__ satt,
    const float* __restrict__ g, const float* __restrict__ b,
    float* __restrict__ x1)
{
    int wv = threadIdx.x >> 6, lane = threadIdx.x & 63;
    int n = blockIdx.x*4 + wv;
    if (n >= N_NODES) return;
    int d0 = lane*2;
    float2 hv = *(const float2*)(h    + (size_t)n*DIM + d0);
    float2 av = *(const float2*)(satt + (size_t)n*DIM + d0);
    float t0 = hv.x + av.x, t1 = hv.y + av.y;
    float sum = t0 + t1, ss = t0*t0 + t1*t1;
    #pragma unroll
    for (int off = 1; off < 64; off <<= 1){
        sum += __shfl_xor(sum, off);
        ss  += __shfl_xor(ss,  off);
    }
    float mu = sum * (1.f/DIM);
    float rstd = rsqrtf(ss*(1.f/DIM) - mu*mu + LN_EPS);
    float2 o = make_float2((t0-mu)*rstd*g[d0]   + b[d0],
                           (t1-mu)*rstd*g[d0+1] + b[d0+1]);
    *(float2*)(x1 + (size_t)n*DIM + d0) = o;
}

// ---------------- fused FFN + LN + LN + act + residual ----------------
__global__ __launch_bounds__(256) void ffn_kernel(
    const float* __restrict__ x1,
    const float* __restrict__ W1, const float* __restrict__ b1,
    const float* __restrict__ W2, const float* __restrict__ b2,
    const float* __restrict__ n2g, const float* __restrict__ n2b,
    const float* __restrict__ lng, const float* __restrict__ lnb,
    int apply_act, float* __restrict__ hbuf)
{
    __shared__ float xs[32][DIM+2];
    __shared__ float ms[32][2*DIM+2];
    int row0 = blockIdx.x*32;
    for (int i = threadIdx.x; i < 32*32; i += 256){
        int r = i >> 5, c4 = (i & 31)*4;
        int row = row0 + r;
        float4 val = make_float4(0.f,0.f,0.f,0.f);
        if (row < N_NODES) val = *(const float4*)(x1 + (size_t)row*DIM + c4);
        xs[r][c4+0]=val.x; xs[r][c4+1]=val.y; xs[r][c4+2]=val.z; xs[r][c4+3]=val.w;
    }
    __syncthreads();
    int rowg = threadIdx.x >> 5;   // 8 groups x 4 rows
    int colg = threadIdx.x & 31;
    {   // GEMM1: mid = leaky(x1 @ W1 + b1), cols colg*8..+7
        float acc[4][8];
        #pragma unroll
        for (int r=0;r<4;++r)
            #pragma unroll
            for (int c=0;c<8;++c) acc[r][c] = 0.f;
        for (int kk = 0; kk < DIM; kk += 2){
            float4 w0A = *(const float4*)(W1 + (size_t)kk*2*DIM + colg*8);
            float4 w1A = *(const float4*)(W1 + (size_t)kk*2*DIM + colg*8 + 4);
            float4 w0B = *(const float4*)(W1 + (size_t)(kk+1)*2*DIM + colg*8);
            float4 w1B = *(const float4*)(W1 + (size_t)(kk+1)*2*DIM + colg*8 + 4);
            #pragma unroll
            for (int r=0;r<4;++r){
                float2 xv = *(const float2*)&xs[rowg*4+r][kk];
                acc[r][0] += xv.x*w0A.x + xv.y*w0B.x;
                acc[r][1] += xv.x*w0A.y + xv.y*w0B.y;
                acc[r][2] += xv.x*w0A.z + xv.y*w0B.z;
                acc[r][3] += xv.x*w0A.w + xv.y*w0B.w;
                acc[r][4] += xv.x*w1A.x + xv.y*w1B.x;
                acc[r][5] += xv.x*w1A.y + xv.y*w1B.y;
                acc[r][6] += xv.x*w1A.z + xv.y*w1B.z;
                acc[r][7] += xv.x*w1A.w + xv.y*w1B.w;
            }
        }
        #pragma unroll
        for (int r=0;r<4;++r)
            #pragma unroll
            for (int c=0;c<8;++c){
                float t = acc[r][c] + b1[colg*8+c];
                ms[rowg*4+r][colg*8+c] = leaky(t);
            }
    }
    __syncthreads();
    // GEMM2: ff = mid @ W2 + b2, cols colg*4..+3, K=256
    float acc2[4][4];
    #pragma unroll
    for (int r=0;r<4;++r){ acc2[r][0]=0.f; acc2[r][1]=0.f; acc2[r][2]=0.f; acc2[r][3]=0.f; }
    for (int kk = 0; kk < 2*DIM; kk += 2){
        float4 wA = *(const float4*)(W2 + (size_t)kk*DIM + colg*4);
        float4 wB = *(const float4*)(W2 + (size_t)(kk+1)*DIM + colg*4);
        #pragma unroll
        for (int r=0;r<4;++r){
            float2 mv = *(const float2*)&ms[rowg*4+r][kk];
            acc2[r][0] += mv.x*wA.x + mv.y*wB.x;
            acc2[r][1] += mv.x*wA.y + mv.y*wB.y;
            acc2[r][2] += mv.x*wA.z + mv.y*wB.z;
            acc2[r][3] += mv.x*wA.w + mv.y*wB.w;
        }
    }
    int j0 = colg*4;
    const float4 bb  = *(const float4*)(b2  + j0);
    const float4 g2  = *(const float4*)(n2g + j0);
    const float4 be2 = *(const float4*)(n2b + j0);
    const float4 gl  = *(const float4*)(lng + j0);
    const float4 bl  = *(const float4*)(lnb + j0);
    #pragma unroll
    for (int r=0;r<4;++r){
        int rr = rowg*4 + r;
        int row = row0 + rr;
        float t0 = xs[rr][j0+0] + acc2[r][0] + bb.x;
        float t1 = xs[rr][j0+1] + acc2[r][1] + bb.y;
        float t2 = xs[rr][j0+2] + acc2[r][2] + bb.z;
        float t3 = xs[rr][j0+3] + acc2[r][3] + bb.w;
        float sum = t0+t1+t2+t3, ss = t0*t0+t1*t1+t2*t2+t3*t3;
        #pragma unroll
        for (int off = 1; off < 32; off <<= 1){
            sum += __shfl_xor(sum, off);
            ss  += __shfl_xor(ss,  off);
        }
        float mu = sum*(1.f/DIM);
        float rstd = rsqrtf(ss*(1.f/DIM) - mu*mu + LN_EPS);
        float c0 = (t0-mu)*rstd*g2.x + be2.x;
        float c1 = (t1-mu)*rstd*g2.y + be2.y;
        float c2 = (t2-mu)*rstd*g2.z + be2.z;
        float c3 = (t3-mu)*rstd*g2.w + be2.w;
        float sum2 = c0+c1+c2+c3, ss2 = c0*c0+c1*c1+c2*c2+c3*c3;
        #pragma unroll
        for (int off = 1; off < 32; off <<= 1){
            sum2 += __shfl_xor(sum2, off);
            ss2  += __shfl_xor(ss2,  off);
        }
        float mu2 = sum2*(1.f/DIM);
        float rstd2 = rsqrtf(ss2*(1.f/DIM) - mu2*mu2 + LN_EPS);
        float h0 = (c0-mu2)*rstd2*gl.x + bl.x;
        float h1 = (c1-mu2)*rstd2*gl.y + bl.y;
        float h2 = (c2-mu2)*rstd2*gl.z + bl.z;
        float h3 = (c3-mu2)*rstd2*gl.w + bl.w;
        if (apply_act){ h0=leaky(h0); h1=leaky(h1); h2=leaky(h2); h3=leaky(h3); }
        if (row < N_NODES){
            float4 hin = *(const float4*)(hbuf + (size_t)row*DIM + j0);
            float4 o = make_float4(h0+hin.x, h1+hin.y, h2+hin.z, h3+hin.w);
            *(float4*)(hbuf + (size_t)row*DIM + j0) = o;
        }
    }
}

extern "C" void kernel_launch(void* const* d_in, const int* in_sizes, int n_in,
                              void* d_out, int out_size, void* d_ws, size_t ws_size,
                              hipStream_t stream)
{
    const int*   edge_index = (const int*)  d_in[1];
    const float* edge_attr  = (const float*)d_in[2];
    const float* node_table = (const float*)d_in[3];
    const float* Wee = (const float*)d_in[4];
    const float* bee = (const float*)d_in[5];
    const float* Wq  = (const float*)d_in[6];  const float* bq = (const float*)d_in[7];
    const float* Wk  = (const float*)d_in[8];  const float* bk = (const float*)d_in[9];
    const float* Wv  = (const float*)d_in[10]; const float* bv = (const float*)d_in[11];
    const float* We  = (const float*)d_in[12]; const float* be = (const float*)d_in[13];
    const float* Ws  = (const float*)d_in[14]; const float* bs = (const float*)d_in[15];
    const float* W1  = (const float*)d_in[16]; const float* b1 = (const float*)d_in[17];
    const float* W2  = (const float*)d_in[18]; const float* b2 = (const float*)d_in[19];
    const float* n1g = (const float*)d_in[20]; const float* n1b = (const float*)d_in[21];
    const float* n2g = (const float*)d_in[22]; const float* n2b = (const float*)d_in[23];
    const float* lng = (const float*)d_in[24]; const float* lnb = (const float*)d_in[25];

    float* h = (float*)d_out;   // h lives in d_out across layers

    char* ws = (char*)d_ws;
    size_t off = 0;
    auto alloc = [&](size_t bytes)->void*{
        void* p = ws + off;
        off += (bytes + 255) & ~(size_t)255;
        return p;
    };
    float* q    = (float*)alloc(sizeof(float)*(size_t)N_NODES*DIM);
    float* k    = (float*)alloc(sizeof(float)*(size_t)N_NODES*DIM);
    float* v    = (float*)alloc(sizeof(float)*(size_t)N_NODES*DIM);
    float* satt = (float*)alloc(sizeof(float)*(size_t)N_NODES*DIM);
    float* eas  = (float*)alloc(sizeof(float)*(size_t)N_EDGES*8);
    float* Weff = (float*)alloc(sizeof(float)*8*DIM);
    int* rowptr = (int*)alloc(sizeof(int)*(N_NODES+1));
    int* cnt    = (int*)alloc(sizeof(int)*N_NODES);
    int* fill   = (int*)alloc(sizeof(int)*N_NODES);
    int* srcs   = (int*)alloc(sizeof(int)*N_EDGES);
    float* x1   = q;   // q is dead once attention is done; reuse for x1

    const int* srcIdx = edge_index;
    const int* dstIdx = edge_index + N_EDGES;

    init_h_kernel<<<(N_NODES*DIM+255)/256, 256, 0, stream>>>(node_table, h);
    zero2_kernel<<<(N_NODES+255)/256, 256, 0, stream>>>(cnt, fill);
    count_kernel<<<(N_EDGES+255)/256, 256, 0, stream>>>(dstIdx, cnt);
    scan_kernel<<<1, 1024, 0, stream>>>(cnt, rowptr);
    scatter_kernel<<<(N_EDGES+255)/256, 256, 0, stream>>>(srcIdx, dstIdx, edge_attr,
                                                          rowptr, fill, srcs, eas);

    for (int l = 0; l < NLAYER; ++l){
        weff_kernel<<<1, 128, 0, stream>>>(Wee, bee, We + (size_t)l*DIM*DIM,
                                           be + (size_t)l*DIM, Weff);
        gemm_qkvs_kernel<<<(N_NODES+63)/64, 256, 0, stream>>>(h,
            Wq + (size_t)l*DIM*DIM, bq + (size_t)l*DIM,
            Wk + (size_t)l*DIM*DIM, bk + (size_t)l*DIM,
            Wv + (size_t)l*DIM*DIM, bv + (size_t)l*DIM,
            Ws + (size_t)l*DIM*DIM, bs + (size_t)l*DIM,
            q, k, v, satt);
        attn_kernel<<<(N_NODES+3)/4, 256, 0, stream>>>(q, k, v, Weff, rowptr, srcs, eas, satt);
        x1_kernel<<<(N_NODES+3)/4, 256, 0, stream>>>(h, satt,
            n1g + (size_t)l*DIM, n1b + (size_t)l*DIM, x1);
        ffn_kernel<<<(N_NODES+31)/32, 256, 0, stream>>>(x1,
            W1 + (size_t)l*DIM*2*DIM, b1 + (size_t)l*2*DIM,
            W2 + (size_t)l*2*DIM*DIM, b2 + (size_t)l*DIM,
            n2g + (size_t)l*DIM, n2b + (size_t)l*DIM,
            lng + (size_t)l*DIM, lnb + (size_t)l*DIM,
            (l < NLAYER-1) ? 1 : 0, h);
    }
}

// Round 2
// 916.629 us; speedup vs baseline: 1.9721x; 1.9721x over previous
//
#include <hip/hip_runtime.h>
#include <hip/hip_bf16.h>
#include <math.h>

#define N_NODES 50000
#define N_EDGES 500000
#define DIM     128
#define NLAYER  4
#define NEFEAT  7

static constexpr float LN_EPS    = 1e-5f;
static constexpr float ATT_SCALE = 0.17677669529663687f;  // 1/sqrt(32)

typedef short s16x8 __attribute__((ext_vector_type(8)));   // 8 bf16 (4 VGPR) MFMA A/B frag
typedef float f32x4 __attribute__((ext_vector_type(4)));   // MFMA C/D frag

static __device__ __forceinline__ float leaky(float x){ return x >= 0.f ? x : 0.01f*x; }

static __device__ __forceinline__ unsigned short f2bf(float f){
    __hip_bfloat16 b = __float2bfloat16(f);
    return *reinterpret_cast<unsigned short*>(&b);
}
static __device__ __forceinline__ float bf2f(unsigned short u){
    __hip_bfloat16 b = *reinterpret_cast<__hip_bfloat16*>(&u);
    return __bfloat162float(b);
}

// ---------------- init h = node_table[0] broadcast (fp32 + bf16 shadow) ----------------
__global__ void init_h_kernel(const float* __restrict__ node_table,
                              float* __restrict__ h, unsigned short* __restrict__ hb){
    int i = blockIdx.x*blockDim.x + threadIdx.x;
    if (i < N_NODES*DIM){
        float v = node_table[i & (DIM-1)];
        h[i]  = v;
        hb[i] = f2bf(v);
    }
}

// ---------------- CSR build ----------------
__global__ void zero2_kernel(int* __restrict__ a, int* __restrict__ b){
    int i = blockIdx.x*blockDim.x + threadIdx.x;
    if (i < N_NODES){ a[i] = 0; b[i] = 0; }
}

__global__ void count_kernel(const int* __restrict__ dst, int* __restrict__ cnt){
    int e = blockIdx.x*blockDim.x + threadIdx.x;
    if (e < N_EDGES) atomicAdd(&cnt[dst[e]], 1);
}

__global__ void scan_kernel(const int* __restrict__ cnt, int* __restrict__ rowptr){
    __shared__ int wsum[16];
    __shared__ int runsh;
    if (threadIdx.x == 0) runsh = 0;
    __syncthreads();
    int lane = threadIdx.x & 63, wid = threadIdx.x >> 6;
    for (int base = 0; base < N_NODES; base += 1024){
        int i = base + (int)threadIdx.x;
        int vv = (i < N_NODES) ? cnt[i] : 0;
        int s = vv;
        #pragma unroll
        for (int off = 1; off < 64; off <<= 1){
            int t = __shfl_up(s, off);
            if (lane >= off) s += t;
        }
        if (lane == 63) wsum[wid] = s;
        __syncthreads();
        if (wid == 0 && lane < 16){
            int x = wsum[lane];
            #pragma unroll
            for (int off = 1; off < 16; off <<= 1){
                int t = __shfl_up(x, off);
                if (lane >= off) x += t;
            }
            wsum[lane] = x;
        }
        __syncthreads();
        int wpre = (wid == 0) ? 0 : wsum[wid-1];
        int run  = runsh;
        if (i < N_NODES) rowptr[i] = run + wpre + s - vv;   // exclusive
        __syncthreads();
        if (threadIdx.x == 0) runsh = run + wsum[15];
        __syncthreads();
    }
    if (threadIdx.x == 0) rowptr[N_NODES] = runsh;
}

__global__ void scatter_kernel(const int* __restrict__ src, const int* __restrict__ dst,
                               const float* __restrict__ edge_attr,
                               const int* __restrict__ rowptr, int* __restrict__ fill,
                               int* __restrict__ srcs, float* __restrict__ eas){
    int e = blockIdx.x*blockDim.x + threadIdx.x;
    if (e >= N_EDGES) return;
    int d   = dst[e];
    int pos = rowptr[d] + atomicAdd(&fill[d], 1);
    srcs[pos] = src[e];
    float*       o = eas + (size_t)pos*8;
    const float* a = edge_attr + (size_t)e*NEFEAT;
    #pragma unroll
    for (int c = 0; c < NEFEAT; ++c) o[c] = a[c];
    o[7] = 1.0f;   // bias slot
}

// ---------------- Weff[l] = [Wee@We_l ; bee@We_l + be_l]  (8 x 128), all layers ----------
__global__ void weff_all_kernel(const float* __restrict__ Wee, const float* __restrict__ bee,
                                const float* __restrict__ We, const float* __restrict__ be,
                                float* __restrict__ weff){
    int l = blockIdx.x;
    int d = threadIdx.x;  // 128 threads
    const float* We_l = We + (size_t)l*DIM*DIM;
    float* out = weff + (size_t)l*8*DIM;
    for (int c = 0; c < NEFEAT; ++c){
        float s = 0.f;
        for (int t = 0; t < DIM; ++t) s += Wee[c*DIM + t] * We_l[t*DIM + d];
        out[c*DIM + d] = s;
    }
    float s = 0.f;
    for (int t = 0; t < DIM; ++t) s += bee[t] * We_l[t*DIM + d];
    out[7*DIM + d] = s + be[l*DIM + d];
}

// ---------------- weight prep: bf16 transposed copies ----------------
// wqkvsT [L][512][128] (n<128:q, <256:k, <384:v, <512:s), w1T [L][256][128], w2T [L][128][256]
__global__ void prepw_kernel(const float* __restrict__ Wq, const float* __restrict__ Wk,
                             const float* __restrict__ Wv, const float* __restrict__ Ws,
                             const float* __restrict__ W1, const float* __restrict__ W2,
                             unsigned short* __restrict__ wqkvsT,
                             unsigned short* __restrict__ w1T,
                             unsigned short* __restrict__ w2T){
    int tid = blockIdx.x*blockDim.x + threadIdx.x;
    if (tid >= NLAYER*131072) return;
    int l = tid >> 17;
    int r = tid & 131071;
    if (r < 65536){
        int n = r >> 7, k = r & 127;
        int p = n >> 7, nn = n & 127;
        const float* W = (p==0)?Wq:(p==1)?Wk:(p==2)?Wv:Ws;
        float val = W[(size_t)l*DIM*DIM + (size_t)k*DIM + nn];
        wqkvsT[(size_t)l*65536 + (size_t)n*128 + k] = f2bf(val);
    } else if (r < 98304){
        int r2 = r - 65536;
        int n = r2 >> 7, k = r2 & 127;
        float val = W1[(size_t)l*32768 + (size_t)k*256 + n];
        w1T[(size_t)l*32768 + (size_t)n*128 + k] = f2bf(val);
    } else {
        int r2 = r - 98304;
        int n = r2 >> 8, k = r2 & 255;
        float val = W2[(size_t)l*32768 + (size_t)k*128 + n];
        w2T[(size_t)l*32768 + (size_t)n*256 + k] = f2bf(val);
    }
}

// ---------------- QKVS GEMM via MFMA: [N,128]bf16 @ [128,512]bf16 ----------------
// grid (tiles=ceil(N/64), 2); block 256 = 4 waves. Wave w covers 64 rows x 64 cols.
__global__ __launch_bounds__(256) void qkvs_mfma_kernel(
    const unsigned short* __restrict__ hb, const unsigned short* __restrict__ wT,
    const float* __restrict__ bq, const float* __restrict__ bk,
    const float* __restrict__ bv, const float* __restrict__ bs,
    unsigned short* __restrict__ q, unsigned short* __restrict__ k,
    unsigned short* __restrict__ v, float* __restrict__ satt)
{
    __shared__ char sA[64*256];   // [64][128] bf16, XOR-swizzled
    int row0 = blockIdx.x*64;
    // stage A tile
    for (int idx = threadIdx.x; idx < 1024; idx += 256){
        int row = idx >> 4, k16 = idx & 15;
        int byte = row*256 + k16*16;  byte ^= (row & 7) << 4;
        s16x8 val = {0,0,0,0,0,0,0,0};
        int grow = row0 + row;
        if (grow < N_NODES) val = *(const s16x8*)(hb + (size_t)grow*128 + k16*8);
        *(s16x8*)(sA + byte) = val;
    }
    __syncthreads();

    int w = threadIdx.x >> 6, l = threadIdx.x & 63;
    int n0 = blockIdx.y*256 + w*64;   // global output column base for this wave
    f32x4 acc[4][4];
    #pragma unroll
    for (int rf=0;rf<4;++rf)
        #pragma unroll
        for (int cf=0;cf<4;++cf) acc[rf][cf] = (f32x4){0.f,0.f,0.f,0.f};

    s16x8 af[2][4], bf[2][4];
    #pragma unroll
    for (int rf=0;rf<4;++rf){
        int row = rf*16 + (l & 15);
        int byte = row*256 + (l >> 4)*16;  byte ^= (row & 7) << 4;
        af[0][rf] = *(const s16x8*)(sA + byte);
    }
    #pragma unroll
    for (int cf=0;cf<4;++cf){
        int n = n0 + cf*16 + (l & 15);
        bf[0][cf] = *(const s16x8*)(wT + (size_t)n*128 + (l >> 4)*8);
    }
    #pragma unroll
    for (int kb = 0; kb < 4; ++kb){
        int cur = kb & 1, nxt = cur ^ 1;
        if (kb < 3){
            #pragma unroll
            for (int rf=0;rf<4;++rf){
                int row = rf*16 + (l & 15);
                int byte = row*256 + (kb+1)*64 + (l >> 4)*16;  byte ^= (row & 7) << 4;
                af[nxt][rf] = *(const s16x8*)(sA + byte);
            }
            #pragma unroll
            for (int cf=0;cf<4;++cf){
                int n = n0 + cf*16 + (l & 15);
                bf[nxt][cf] = *(const s16x8*)(wT + (size_t)n*128 + (kb+1)*32 + (l >> 4)*8);
            }
        }
        #pragma unroll
        for (int rf=0;rf<4;++rf)
            #pragma unroll
            for (int cf=0;cf<4;++cf)
                acc[rf][cf] = __builtin_amdgcn_mfma_f32_16x16x32_bf16(af[cur][rf], bf[cur][cf], acc[rf][cf], 0, 0, 0);
    }

    // epilogue
    int part = n0 >> 7;                      // 0:q 1:k 2:v 3:s
    int cip0 = n0 & 127;                     // col base within part
    const float* bias = (part==0)?bq:(part==1)?bk:(part==2)?bv:bs;
    unsigned short* outp = (part==0)?q:(part==1)?k:v;
    #pragma unroll
    for (int cf=0;cf<4;++cf){
        int col = cip0 + cf*16 + (l & 15);
        float bb = bias[col];
        #pragma unroll
        for (int rf=0;rf<4;++rf){
            #pragma unroll
            for (int r=0;r<4;++r){
                int row = row0 + rf*16 + ((l >> 4) << 2) + r;
                if (row < N_NODES){
                    float val = acc[rf][cf][r] + bb;
                    if (part == 3) satt[(size_t)row*128 + col] = val;
                    else           outp[(size_t)row*128 + col] = f2bf(val);
                }
            }
        }
    }
}

// ---------------- attention + skip + LN1 fused: one wave per destination node -----------
__global__ __launch_bounds__(256) void attn_kernel(
    const unsigned short* __restrict__ qq, const unsigned short* __restrict__ kk,
    const unsigned short* __restrict__ vv,
    const float* __restrict__ weff_l, const int* __restrict__ rowptr,
    const int* __restrict__ srcs, const float* __restrict__ eas,
    const float* __restrict__ satt, const float* __restrict__ h,
    const float* __restrict__ n1g, const float* __restrict__ n1b,
    float* __restrict__ x1, unsigned short* __restrict__ x1b)
{
    __shared__ float wf[8][DIM];
    for (int i = threadIdx.x; i < 8*DIM; i += 256) ((float*)wf)[i] = weff_l[i];
    __syncthreads();
    int wv = threadIdx.x >> 6, lane = threadIdx.x & 63;
    int n = blockIdx.x*4 + wv;
    if (n >= N_NODES) return;
    int d0 = lane*2;
    unsigned int qb = *(const unsigned int*)(qq + (size_t)n*DIM + d0);
    float q0 = bf2f((unsigned short)(qb & 0xFFFF)), q1 = bf2f((unsigned short)(qb >> 16));
    int beg = rowptr[n], end = rowptr[n+1];
    float m = -INFINITY, den = 0.f, a0 = 0.f, a1 = 0.f;
    for (int i = beg; i < end; ++i){
        int sv = srcs[i];
        unsigned int kb_ = *(const unsigned int*)(kk + (size_t)sv*DIM + d0);
        unsigned int vb_ = *(const unsigned int*)(vv + (size_t)sv*DIM + d0);
        float k0 = bf2f((unsigned short)(kb_ & 0xFFFF)), k1 = bf2f((unsigned short)(kb_ >> 16));
        float v0 = bf2f((unsigned short)(vb_ & 0xFFFF)), v1 = bf2f((unsigned short)(vb_ >> 16));
        const float* ea = eas + (size_t)i*8;
        float e0 = 0.f, e1 = 0.f;
        #pragma unroll
        for (int c = 0; c < 8; ++c){
            float ec = ea[c];
            float2 wc = *(const float2*)&wf[c][d0];
            e0 += ec*wc.x; e1 += ec*wc.y;
        }
        float part = q0*(k0+e0) + q1*(k1+e1);
        part += __shfl_xor(part, 1);
        part += __shfl_xor(part, 2);
        part += __shfl_xor(part, 4);
        part += __shfl_xor(part, 8);   // per-head (16-lane) dot
        float alpha = part * ATT_SCALE;
        float nm = fmaxf(m, alpha);
        float f  = __expf(m - nm);
        float p  = __expf(alpha - nm);
        den = den*f + p;
        a0  = a0*f  + p*(v0+e0);
        a1  = a1*f  + p*(v1+e1);
        m = nm;
    }
    float inv = (den > 0.f) ? 1.f/den : 0.f;
    float2 sv2 = *(const float2*)(satt + (size_t)n*DIM + d0);
    float2 hv  = *(const float2*)(h    + (size_t)n*DIM + d0);
    float t0 = hv.x + a0*inv + sv2.x;
    float t1 = hv.y + a1*inv + sv2.y;
    // LN1
    float sum = t0 + t1, ss = t0*t0 + t1*t1;
    #pragma unroll
    for (int off = 1; off < 64; off <<= 1){
        sum += __shfl_xor(sum, off);
        ss  += __shfl_xor(ss,  off);
    }
    float mu = sum * (1.f/DIM);
    float rstd = rsqrtf(ss*(1.f/DIM) - mu*mu + LN_EPS);
    float o0 = (t0-mu)*rstd*n1g[d0]   + n1b[d0];
    float o1 = (t1-mu)*rstd*n1g[d0+1] + n1b[d0+1];
    *(float2*)(x1 + (size_t)n*DIM + d0) = make_float2(o0, o1);
    unsigned int pk = (unsigned int)f2bf(o0) | ((unsigned int)f2bf(o1) << 16);
    *(unsigned int*)(x1b + (size_t)n*DIM + d0) = pk;
}

// ---------------- FFN via MFMA + LN2 + LN3 + act + residual ----------------
// grid ceil(N/64); block 256 = 4 waves; 64-row tile.
__global__ __launch_bounds__(256) void ffn_mfma_kernel(
    const unsigned short* __restrict__ x1b, const float* __restrict__ x1,
    const float* __restrict__ hin,
    const unsigned short* __restrict__ w1T, const float* __restrict__ b1,
    const unsigned short* __restrict__ w2T, const float* __restrict__ b2,
    const float* __restrict__ n2g, const float* __restrict__ n2b,
    const float* __restrict__ lng, const float* __restrict__ lnb,
    int apply_act, float* __restrict__ h, unsigned short* __restrict__ hb)
{
    __shared__ char smem[49152];
    char* sA   = smem;            // [64][128] bf16 swz (x1 tile)          16 KB
    char* sMid = smem + 16384;    // [64][256] bf16 swz (mid) -> later ffout [64][128] f32 swz (32 KB)
    int row0 = blockIdx.x*64;
    for (int idx = threadIdx.x; idx < 1024; idx += 256){
        int row = idx >> 4, k16 = idx & 15;
        int byte = row*256 + k16*16;  byte ^= (row & 7) << 4;
        s16x8 val = {0,0,0,0,0,0,0,0};
        int grow = row0 + row;
        if (grow < N_NODES) val = *(const s16x8*)(x1b + (size_t)grow*128 + k16*8);
        *(s16x8*)(sA + byte) = val;
    }
    __syncthreads();

    int w = threadIdx.x >> 6, l = threadIdx.x & 63;

    // ---- GEMM1: mid[64][256] = leaky(x1 @ W1 + b1); wave w -> cols w*64..+63
    {
        int n0 = w*64;
        f32x4 acc[4][4];
        #pragma unroll
        for (int rf=0;rf<4;++rf)
            #pragma unroll
            for (int cf=0;cf<4;++cf) acc[rf][cf] = (f32x4){0.f,0.f,0.f,0.f};
        s16x8 af[2][4], bfr[2][4];
        #pragma unroll
        for (int rf=0;rf<4;++rf){
            int row = rf*16 + (l & 15);
            int byte = row*256 + (l >> 4)*16;  byte ^= (row & 7) << 4;
            af[0][rf] = *(const s16x8*)(sA + byte);
        }
        #pragma unroll
        for (int cf=0;cf<4;++cf){
            int n = n0 + cf*16 + (l & 15);
            bfr[0][cf] = *(const s16x8*)(w1T + (size_t)n*128 + (l >> 4)*8);
        }
        #pragma unroll
        for (int kb = 0; kb < 4; ++kb){
            int cur = kb & 1, nxt = cur ^ 1;
            if (kb < 3){
                #pragma unroll
                for (int rf=0;rf<4;++rf){
                    int row = rf*16 + (l & 15);
                    int byte = row*256 + (kb+1)*64 + (l >> 4)*16;  byte ^= (row & 7) << 4;
                    af[nxt][rf] = *(const s16x8*)(sA + byte);
                }
                #pragma unroll
                for (int cf=0;cf<4;++cf){
                    int n = n0 + cf*16 + (l & 15);
                    bfr[nxt][cf] = *(const s16x8*)(w1T + (size_t)n*128 + (kb+1)*32 + (l >> 4)*8);
                }
            }
            #pragma unroll
            for (int rf=0;rf<4;++rf)
                #pragma unroll
                for (int cf=0;cf<4;++cf)
                    acc[rf][cf] = __builtin_amdgcn_mfma_f32_16x16x32_bf16(af[cur][rf], bfr[cur][cf], acc[rf][cf], 0, 0, 0);
        }
        #pragma unroll
        for (int cf=0;cf<4;++cf){
            int col = n0 + cf*16 + (l & 15);
            float bb = b1[col];
            #pragma unroll
            for (int rf=0;rf<4;++rf){
                #pragma unroll
                for (int r=0;r<4;++r){
                    int row = rf*16 + ((l >> 4) << 2) + r;
                    float val = leaky(acc[rf][cf][r] + bb);
                    int byte = row*512 + col*2;  byte ^= (row & 7) << 4;
                    *(unsigned short*)(sMid + byte) = f2bf(val);
                }
            }
        }
    }
    __syncthreads();

    // ---- GEMM2: ff[64][128] = mid @ W2; wave w -> cols w*32..+31; K=256
    f32x4 acc2[2][4];
    {
        int n0 = w*32;
        #pragma unroll
        for (int cf=0;cf<2;++cf)
            #pragma unroll
            for (int rf=0;rf<4;++rf) acc2[cf][rf] = (f32x4){0.f,0.f,0.f,0.f};
        s16x8 af[2][4], bfr[2][2];
        #pragma unroll
        for (int rf=0;rf<4;++rf){
            int row = rf*16 + (l & 15);
            int byte = row*512 + (l >> 4)*16;  byte ^= (row & 7) << 4;
            af[0][rf] = *(const s16x8*)(sMid + byte);
        }
        #pragma unroll
        for (int cf=0;cf<2;++cf){
            int n = n0 + cf*16 + (l & 15);
            bfr[0][cf] = *(const s16x8*)(w2T + (size_t)n*256 + (l >> 4)*8);
        }
        #pragma unroll
        for (int kb = 0; kb < 8; ++kb){
            int cur = kb & 1, nxt = cur ^ 1;
            if (kb < 7){
                #pragma unroll
                for (int rf=0;rf<4;++rf){
                    int row = rf*16 + (l & 15);
                    int byte = row*512 + (kb+1)*64 + (l >> 4)*16;  byte ^= (row & 7) << 4;
                    af[nxt][rf] = *(const s16x8*)(sMid + byte);
                }
                #pragma unroll
                for (int cf=0;cf<2;++cf){
                    int n = n0 + cf*16 + (l & 15);
                    bfr[nxt][cf] = *(const s16x8*)(w2T + (size_t)n*256 + (kb+1)*32 + (l >> 4)*8);
                }
            }
            #pragma unroll
            for (int cf=0;cf<2;++cf)
                #pragma unroll
                for (int rf=0;rf<4;++rf)
                    acc2[cf][rf] = __builtin_amdgcn_mfma_f32_16x16x32_bf16(af[cur][rf], bfr[cur][cf], acc2[cf][rf], 0, 0, 0);
        }
    }
    __syncthreads();   // all GEMM2 reads of sMid done; reuse as ffout f32

    float* sFF = (float*)sMid;    // [64][128] f32, swz, byte = row*512 + col*4 ^ ((row&7)<<4)
    {
        int n0 = w*32;
        #pragma unroll
        for (int cf=0;cf<2;++cf){
            int col = n0 + cf*16 + (l & 15);
            float bb = b2[col];
            #pragma unroll
            for (int rf=0;rf<4;++rf){
                #pragma unroll
                for (int r=0;r<4;++r){
                    int row = rf*16 + ((l >> 4) << 2) + r;
                    int byte = row*512 + col*4;  byte ^= (row & 7) << 4;
                    *(float*)((char*)sFF + byte) = acc2[cf][rf][r] + bb;
                }
            }
        }
    }
    __syncthreads();

    // ---- LN chain: c = LN2(x1+ff), hn = LN3(c), act, h = hn + h_in
    int d0 = l*2;
    float g2a = n2g[d0], g2b = n2g[d0+1], be2a = n2b[d0], be2b = n2b[d0+1];
    float gla = lng[d0], glb = lng[d0+1], bla = lnb[d0], blb = lnb[d0+1];
    for (int i = 0; i < 16; ++i){
        int rr = w*16 + i;
        int grow = row0 + rr;
        if (grow >= N_NODES) break;
        int byte = rr*512 + d0*4;  byte ^= (rr & 7) << 4;
        float2 ff = *(float2*)((char*)sFF + byte);
        float2 xr = *(const float2*)(x1  + (size_t)grow*DIM + d0);
        float2 hr = *(const float2*)(hin + (size_t)grow*DIM + d0);
        float t0 = xr.x + ff.x, t1 = xr.y + ff.y;
        float sum = t0 + t1, ss = t0*t0 + t1*t1;
        #pragma unroll
        for (int off = 1; off < 64; off <<= 1){
            sum += __shfl_xor(sum, off);
            ss  += __shfl_xor(ss,  off);
        }
        float mu = sum*(1.f/DIM);
        float rstd = rsqrtf(ss*(1.f/DIM) - mu*mu + LN_EPS);
        float c0 = (t0-mu)*rstd*g2a + be2a;
        float c1 = (t1-mu)*rstd*g2b + be2b;
        float sum2 = c0 + c1, ss2 = c0*c0 + c1*c1;
        #pragma unroll
        for (int off = 1; off < 64; off <<= 1){
            sum2 += __shfl_xor(sum2, off);
            ss2  += __shfl_xor(ss2,  off);
        }
        float mu2 = sum2*(1.f/DIM);
        float rstd2 = rsqrtf(ss2*(1.f/DIM) - mu2*mu2 + LN_EPS);
        float z0 = (c0-mu2)*rstd2*gla + bla;
        float z1 = (c1-mu2)*rstd2*glb + blb;
        if (apply_act){ z0 = leaky(z0); z1 = leaky(z1); }
        float o0 = z0 + hr.x, o1 = z1 + hr.y;
        *(float2*)(h + (size_t)grow*DIM + d0) = make_float2(o0, o1);
        unsigned int pk = (unsigned int)f2bf(o0) | ((unsigned int)f2bf(o1) << 16);
        *(unsigned int*)(hb + (size_t)grow*DIM + d0) = pk;
    }
}

extern "C" void kernel_launch(void* const* d_in, const int* in_sizes, int n_in,
                              void* d_out, int out_size, void* d_ws, size_t ws_size,
                              hipStream_t stream)
{
    const int*   edge_index = (const int*)  d_in[1];
    const float* edge_attr  = (const float*)d_in[2];
    const float* node_table = (const float*)d_in[3];
    const float* Wee = (const float*)d_in[4];
    const float* bee = (const float*)d_in[5];
    const float* Wq  = (const float*)d_in[6];  const float* bq = (const float*)d_in[7];
    const float* Wk  = (const float*)d_in[8];  const float* bk = (const float*)d_in[9];
    const float* Wv  = (const float*)d_in[10]; const float* bv = (const float*)d_in[11];
    const float* We  = (const float*)d_in[12]; const float* be = (const float*)d_in[13];
    const float* Ws  = (const float*)d_in[14]; const float* bs = (const float*)d_in[15];
    const float* W1  = (const float*)d_in[16]; const float* b1 = (const float*)d_in[17];
    const float* W2  = (const float*)d_in[18]; const float* b2 = (const float*)d_in[19];
    const float* n1g = (const float*)d_in[20]; const float* n1b = (const float*)d_in[21];
    const float* n2g = (const float*)d_in[22]; const float* n2b = (const float*)d_in[23];
    const float* lng = (const float*)d_in[24]; const float* lnb = (const float*)d_in[25];

    float* h = (float*)d_out;   // h lives in d_out across layers

    char* ws = (char*)d_ws;
    size_t off = 0;
    auto alloc = [&](size_t bytes)->void*{
        void* p = ws + off;
        off += (bytes + 255) & ~(size_t)255;
        return p;
    };
    unsigned short* q   = (unsigned short*)alloc(sizeof(short)*(size_t)N_NODES*DIM);
    unsigned short* k   = (unsigned short*)alloc(sizeof(short)*(size_t)N_NODES*DIM);
    unsigned short* v   = (unsigned short*)alloc(sizeof(short)*(size_t)N_NODES*DIM);
    unsigned short* hb  = (unsigned short*)alloc(sizeof(short)*(size_t)N_NODES*DIM);
    unsigned short* x1b = (unsigned short*)alloc(sizeof(short)*(size_t)N_NODES*DIM);
    float* satt = (float*)alloc(sizeof(float)*(size_t)N_NODES*DIM);
    float* x1   = (float*)alloc(sizeof(float)*(size_t)N_NODES*DIM);
    float* eas  = (float*)alloc(sizeof(float)*(size_t)N_EDGES*8);
    unsigned short* wqkvsT = (unsigned short*)alloc(sizeof(short)*NLAYER*512*128);
    unsigned short* w1T    = (unsigned short*)alloc(sizeof(short)*NLAYER*256*128);
    unsigned short* w2T    = (unsigned short*)alloc(sizeof(short)*NLAYER*128*256);
    float* weff = (float*)alloc(sizeof(float)*NLAYER*8*DIM);
    int* rowptr = (int*)alloc(sizeof(int)*(N_NODES+1));
    int* cnt    = (int*)alloc(sizeof(int)*N_NODES);
    int* fill   = (int*)alloc(sizeof(int)*N_NODES);
    int* srcs   = (int*)alloc(sizeof(int)*N_EDGES);

    const int* srcIdx = edge_index;
    const int* dstIdx = edge_index + N_EDGES;

    init_h_kernel<<<(N_NODES*DIM+255)/256, 256, 0, stream>>>(node_table, h, hb);
    zero2_kernel<<<(N_NODES+255)/256, 256, 0, stream>>>(cnt, fill);
    count_kernel<<<(N_EDGES+255)/256, 256, 0, stream>>>(dstIdx, cnt);
    scan_kernel<<<1, 1024, 0, stream>>>(cnt, rowptr);
    scatter_kernel<<<(N_EDGES+255)/256, 256, 0, stream>>>(srcIdx, dstIdx, edge_attr,
                                                          rowptr, fill, srcs, eas);
    prepw_kernel<<<(NLAYER*131072+255)/256, 256, 0, stream>>>(Wq, Wk, Wv, Ws, W1, W2,
                                                              wqkvsT, w1T, w2T);
    weff_all_kernel<<<NLAYER, 128, 0, stream>>>(Wee, bee, We, be, weff);

    int tiles = (N_NODES + 63)/64;
    for (int l = 0; l < NLAYER; ++l){
        qkvs_mfma_kernel<<<dim3(tiles, 2), 256, 0, stream>>>(hb,
            wqkvsT + (size_t)l*65536,
            bq + (size_t)l*DIM, bk + (size_t)l*DIM, bv + (size_t)l*DIM, bs + (size_t)l*DIM,
            q, k, v, satt);
        attn_kernel<<<(N_NODES+3)/4, 256, 0, stream>>>(q, k, v,
            weff + (size_t)l*8*DIM, rowptr, srcs, eas, satt, h,
            n1g + (size_t)l*DIM, n1b + (size_t)l*DIM, x1, x1b);
        ffn_mfma_kernel<<<tiles, 256, 0, stream>>>(x1b, x1, h,
            w1T + (size_t)l*32768, b1 + (size_t)l*2*DIM,
            w2T + (size_t)l*32768, b2 + (size_t)l*DIM,
            n2g + (size_t)l*DIM, n2b + (size_t)l*DIM,
            lng + (size_t)l*DIM, lnb + (size_t)l*DIM,
            (l < NLAYER-1) ? 1 : 0, h, hb);
    }
}